// Round 13
// baseline (178.510 us; speedup 1.0000x reference)
//
#include <hip/hip_runtime.h>

#define B_ 64
#define L_ 256
#define E_ 128
#define C_ 16
#define K_ 5
#define NL_ 4
#define STEP_ 0.1f
#define LOG2E_ 1.4426950408889634f

typedef __bf16 bfh;
typedef __attribute__((ext_vector_type(8))) __bf16 bf16x8;
typedef __attribute__((ext_vector_type(4))) float f32x4;
typedef __attribute__((ext_vector_type(16))) float f32x16;

#define SWZ(r) (((r) ^ ((r) >> 4)) & 15)

#if __has_builtin(__builtin_amdgcn_exp2f)
#define EXP2(x) __builtin_amdgcn_exp2f(x)
#else
static __device__ __forceinline__ float EXP2(float x) {
  float r;
  asm("v_exp_f32 %0, %1\n\ts_nop 0" : "=v"(r) : "v"(x));
  return r;
}
#endif

// ---------------- merged prep: conv weights -> wT[lay][k][o][i]; t1w -> bf16*log2e ----------------
__global__ void k_prep(const float* __restrict__ w, const float* __restrict__ t1w,
                       bfh* __restrict__ wT, bfh* __restrict__ t1wb) {
  int i = blockIdx.x * 256 + threadIdx.x;
  const int NW = NL_ * K_ * E_ * E_;  // 327680
  if (i < NW) {
    int ii = i & 127;
    int rest = i >> 7;
    int o = rest & 127;
    int rest2 = rest >> 7;
    int k = rest2 % K_;
    int lay = rest2 / K_;
    wT[i] = (bfh)w[(((size_t)lay * E_ + o) * E_ + ii) * K_ + k];
    return;
  }
  int j = i - NW;
  if (j < 2048 * 128) t1wb[j] = (bfh)(t1w[j] * LOG2E_);
}

// ---------------- fused conv stack: embed + 4 layers in LDS + frag-layout output ----------------
// grid (8, 64): 32-l output tile per block; 48 staged rows (halo 8). 512 thr, 8 waves.
__global__ __launch_bounds__(512, 2) void k_conv4(const int* __restrict__ aa,
                                                  const float* __restrict__ emb,
                                                  const bfh* __restrict__ wT,
                                                  const float* __restrict__ conv_b,
                                                  bfh* __restrict__ xTg) {
  __shared__ __align__(16) char smem[3 * 12288];
  char* bufIn = smem;
  char* bufA = smem + 12288;
  char* bufB = smem + 24576;
  const int b = blockIdx.y;
  const int lb = blockIdx.x * 32;
  const int t = threadIdx.x;
  const int wv = t >> 6, lane = t & 63;
  const int c16 = lane & 15, kg = lane >> 4;

  // ---- stage 48 embedded rows: row <-> global l = lb-8+row, zeros outside frame ----
  for (int s = t; s < 48 * 16; s += 512) {
    int row = s >> 4, ch = s & 15;
    int lp = lb + row - 8;
    uint4 pk = {0, 0, 0, 0};
    if (lp >= 0 && lp < L_) {
      int idx = aa[b * L_ + lp];
      float4 f0 = *(const float4*)(emb + (size_t)idx * E_ + ch * 8);
      float4 f1 = *(const float4*)(emb + (size_t)idx * E_ + ch * 8 + 4);
      union { bfh h[8]; uint4 u; } cv;
      cv.h[0] = (bfh)f0.x; cv.h[1] = (bfh)f0.y; cv.h[2] = (bfh)f0.z; cv.h[3] = (bfh)f0.w;
      cv.h[4] = (bfh)f1.x; cv.h[5] = (bfh)f1.y; cv.h[6] = (bfh)f1.z; cv.h[7] = (bfh)f1.w;
      pk = cv.u;
    }
    *(uint4*)(bufIn + row * 256 + ((ch ^ (row & 7)) << 4)) = pk;
  }
  __syncthreads();

  // ---- layers 1..3: compute all 48 rows, LDS -> LDS ----
  const char* src = bufIn;
  char* dst = bufA;
#pragma unroll 1
  for (int lay = 0; lay < 3; ++lay) {
    const bfh* wL = wT + (size_t)lay * K_ * E_ * E_;
    const float* bL = conv_b + lay * E_;
#pragma unroll
    for (int j = 0; j < 3; ++j) {
      const int pi = wv * 3 + j;         // 0..23
      const int ot = pi & 7, mt = pi >> 3;
      const int o = ot * 16 + c16;
      f32x4 acc = {0.f, 0.f, 0.f, 0.f};
#pragma unroll
      for (int k = 0; k < K_; ++k) {
        const bfh* bp = wL + ((size_t)(k * E_ + o)) * E_ + kg * 8;
        bf16x8 b0 = *(const bf16x8*)(bp);
        bf16x8 b1 = *(const bf16x8*)(bp + 32);
        bf16x8 b2 = *(const bf16x8*)(bp + 64);
        bf16x8 b3 = *(const bf16x8*)(bp + 96);
        int rt = mt * 16 + c16 + k - 2;
        rt = rt < 0 ? 0 : (rt > 47 ? 47 : rt);  // clamp: garbage rows only
        bf16x8 a0 = *(const bf16x8*)(src + rt * 256 + (((0 * 4 + kg) ^ (rt & 7)) << 4));
        bf16x8 a1 = *(const bf16x8*)(src + rt * 256 + (((1 * 4 + kg) ^ (rt & 7)) << 4));
        bf16x8 a2 = *(const bf16x8*)(src + rt * 256 + (((2 * 4 + kg) ^ (rt & 7)) << 4));
        bf16x8 a3 = *(const bf16x8*)(src + rt * 256 + (((3 * 4 + kg) ^ (rt & 7)) << 4));
        acc = __builtin_amdgcn_mfma_f32_16x16x32_bf16(a0, b0, acc, 0, 0, 0);
        acc = __builtin_amdgcn_mfma_f32_16x16x32_bf16(a1, b1, acc, 0, 0, 0);
        acc = __builtin_amdgcn_mfma_f32_16x16x32_bf16(a2, b2, acc, 0, 0, 0);
        acc = __builtin_amdgcn_mfma_f32_16x16x32_bf16(a3, b3, acc, 0, 0, 0);
      }
      const float bo = bL[o];
#pragma unroll
      for (int r = 0; r < 4; ++r) {
        int ro = mt * 16 + kg * 4 + r;
        int gl = lb - 8 + ro;
        float res = (float)*(const bfh*)(src + ro * 256 +
                                         (((o >> 3) ^ (ro & 7)) << 4) + (o & 7) * 2);
        float v = acc[r] + res + bo;
        float ex = EXP2(2.f * LOG2E_ * v);
        float th = 1.f - 2.f / (ex + 1.f);
        if (gl < 0 || gl >= L_) th = 0.f;  // SAME-padding semantics for next layer
        *(bfh*)(dst + ro * 256 + (((o >> 3) ^ (ro & 7)) << 4) + (o & 7) * 2) = (bfh)th;
      }
    }
    __syncthreads();
    src = dst;
    dst = (lay == 0) ? bufB : bufA;
  }

  // ---- layer 4: 32 output rows, write xTg in frag layout ----
  {
    const bfh* wL = wT + (size_t)3 * K_ * E_ * E_;
    const float* bL = conv_b + 3 * E_;
    const int msub = wv & 1;
    const int nq = wv >> 1;
#pragma unroll
    for (int ntl = 0; ntl < 2; ++ntl) {
      const int n0 = nq * 32 + ntl * 16;
      const int o = n0 + c16;
      f32x4 acc = {0.f, 0.f, 0.f, 0.f};
#pragma unroll
      for (int k = 0; k < K_; ++k) {
        const bfh* bp = wL + ((size_t)(k * E_ + o)) * E_ + kg * 8;
        bf16x8 b0 = *(const bf16x8*)(bp);
        bf16x8 b1 = *(const bf16x8*)(bp + 32);
        bf16x8 b2 = *(const bf16x8*)(bp + 64);
        bf16x8 b3 = *(const bf16x8*)(bp + 96);
        const int rt = msub * 16 + c16 + k + 6;  // (lrow+8)+k-2, in [6,43]
        bf16x8 a0 = *(const bf16x8*)(src + rt * 256 + (((0 * 4 + kg) ^ (rt & 7)) << 4));
        bf16x8 a1 = *(const bf16x8*)(src + rt * 256 + (((1 * 4 + kg) ^ (rt & 7)) << 4));
        bf16x8 a2 = *(const bf16x8*)(src + rt * 256 + (((2 * 4 + kg) ^ (rt & 7)) << 4));
        bf16x8 a3 = *(const bf16x8*)(src + rt * 256 + (((3 * 4 + kg) ^ (rt & 7)) << 4));
        acc = __builtin_amdgcn_mfma_f32_16x16x32_bf16(a0, b0, acc, 0, 0, 0);
        acc = __builtin_amdgcn_mfma_f32_16x16x32_bf16(a1, b1, acc, 0, 0, 0);
        acc = __builtin_amdgcn_mfma_f32_16x16x32_bf16(a2, b2, acc, 0, 0, 0);
        acc = __builtin_amdgcn_mfma_f32_16x16x32_bf16(a3, b3, acc, 0, 0, 0);
      }
      const float bo = bL[o];
      const int kkp = nq * 2 + ntl;
      const int hic = c16 >> 3;
      const int e7 = c16 & 7;
#pragma unroll
      for (int r = 0; r < 4; ++r) {
        int lrow = msub * 16 + kg * 4 + r;
        int ro = lrow + 8;
        float res = (float)*(const bfh*)(src + ro * 256 +
                                         (((o >> 3) ^ (ro & 7)) << 4) + (o & 7) * 2);
        float v = acc[r] + res + bo;
        float ex = EXP2(2.f * LOG2E_ * v);
        float th = 1.f - 2.f / (ex + 1.f);
        size_t el = ((((size_t)b * 8 + blockIdx.x) * 8 + kkp) * 2 + hic) * 256 + lrow * 8 + e7;
        xTg[el] = (bfh)th;
      }
    }
  }
}

// ---------------- x2 GEMM: x2g[b_loc][apair 128][echunk 16][m32 32][8 bf16], frag-ready ----------------
__global__ __launch_bounds__(512, 2) void k_x2(const bfh* __restrict__ xTg,
                                               const bfh* __restrict__ t1wb,
                                               const float* __restrict__ t1b,
                                               bfh* __restrict__ x2g,
                                               int bBase) {
  __shared__ __align__(16) char smem[65536 + 2 * 8192];
  char* XF = smem;
  const unsigned u = blockIdx.x;
  const int xcd = u & 7;
  const int g = u >> 3;
  const int b_loc = xcd + 8 * (g >> 3);
  const int ne = g & 7;
  const int b = bBase + b_loc;
  const int t = threadIdx.x;
  const int wv = t >> 6, lane = t & 63;
  const int c16 = lane & 15, kg = lane >> 4;

#pragma unroll
  for (int i = 0; i < 8; ++i) {
    int c = t + i * 512;
    int l31 = c & 31, hi5 = (c >> 5) & 1, kk = (c >> 6) & 7, dt = c >> 9;
    int row = dt * 32 + l31;
    int ch = (kk * 2 + hi5) ^ SWZ(row);
    *(uint4*)(XF + row * 256 + (ch << 4)) =
        *(const uint4*)(xTg + (size_t)b * 32768 + (size_t)c * 8);
  }
  __syncthreads();

  bf16x8 bf[2][4];
  float bias[2];
#pragma unroll
  for (int j = 0; j < 2; ++j) {
    const int e = ne * 16 + wv * 2 + j;
    const int n = e * 16 + c16;
#pragma unroll
    for (int kk = 0; kk < 4; ++kk)
      bf[j][kk] = *(const bf16x8*)(t1wb + (size_t)n * 128 + kk * 32 + kg * 8);
    bias[j] = t1b[n] * LOG2E_;
  }

#pragma unroll 1
  for (int st = 0; st < 16; ++st) {
    char* sc = smem + 65536 + (st & 1) * 8192;
    bf16x8 a1[4];
    const int rowa = st * 16 + c16;
#pragma unroll
    for (int kk = 0; kk < 4; ++kk)
      a1[kk] = *(const bf16x8*)(XF + rowa * 256 + (((kk * 4 + kg) ^ SWZ(rowa)) << 4));
    f32x4 acc0 = {0.f, 0.f, 0.f, 0.f};
    f32x4 acc1 = {0.f, 0.f, 0.f, 0.f};
#pragma unroll
    for (int kk = 0; kk < 4; ++kk) {
      acc0 = __builtin_amdgcn_mfma_f32_16x16x32_bf16(a1[kk], bf[0][kk], acc0, 0, 0, 0);
      acc1 = __builtin_amdgcn_mfma_f32_16x16x32_bf16(a1[kk], bf[1][kk], acc1, 0, 0, 0);
    }
#pragma unroll
    for (int r = 0; r < 4; ++r) {
      int a = kg * 4 + r;
      int m5 = (c16 & 3) | ((a & 1) << 2) | ((c16 >> 2) << 3);
      int row = (a >> 1) * 32 + m5;
      union { bfh h; ushort s; } lo, hi2;
      lo.h = (bfh)(acc0[r] + bias[0]);
      hi2.h = (bfh)(acc1[r] + bias[1]);
      unsigned pk = (unsigned)lo.s | ((unsigned)hi2.s << 16);
      *(unsigned*)(sc + row * 32 + (((wv) ^ ((row >> 2) & 7)) << 2)) = pk;
    }
    __syncthreads();
    {
      const int m32 = t & 31;
      const int eo = (t >> 5) & 1;
      const int mb = t >> 6;
      const int row = mb * 32 + m32;
      uint4 v;
      unsigned* vp = (unsigned*)&v;
#pragma unroll
      for (int jj = 0; jj < 4; ++jj) {
        int j2 = eo * 4 + jj;
        vp[jj] = *(const unsigned*)(sc + row * 32 + ((j2 ^ ((row >> 2) & 7)) << 2));
      }
      size_t el = (((size_t)(b_loc * 128 + st * 8 + mb)) * 16 + ne * 2 + eo) * 256 + m32 * 8;
      *(uint4*)(x2g + el) = v;
    }
  }
}

// ---------------- pairwise kernel: 512 thr, single-acc chain, native exp2 ----------------
__global__ __launch_bounds__(512, 2) void k_pair(
    const bfh* __restrict__ xTg,
    const float* __restrict__ bb,
    const bfh* __restrict__ x2g,
    const float* __restrict__ t2w,
    const float* __restrict__ t2b,
    float* __restrict__ vkp,       // [b][dh][a][3] f32
    int bBase) {
  __shared__ __align__(16) float bbs[L_ * 3];
  const int t = threadIdx.x;
  const unsigned u = blockIdx.x;
  const int b_loc = (u & 7) | ((u >> 8) << 3);   // XCD-affine: frame's 32 blocks on one XCD
  const int inner = (u >> 3) & 31;
  const int atile = inner >> 1;                  // 0..15
  const int dh = inner & 1;                      // d-half
  const int b = bBase + b_loc;
  const int lane = t & 63;
  const int wv = t >> 6;
  const int l31 = lane & 31;
  const int hi = lane >> 5;

  if (t < 192) ((float4*)bbs)[t] = ((const float4*)(bb + b * (L_ * 3)))[t];
  __syncthreads();

  bf16x8 afr[8];
  const bfh* abase = x2g + ((size_t)(b_loc * 128 + atile * 8 + wv)) * 4096 + l31 * 8;
#pragma unroll
  for (int kk = 0; kk < 8; ++kk)
    afr[kk] = *(const bf16x8*)(abase + (kk * 2 + hi) * 256);

  const int aglob = atile * 16 + 2 * wv + hi;
  const float bax0 = bbs[aglob * 3 + 0];
  const float bax1 = bbs[aglob * 3 + 1];
  const float bax2 = bbs[aglob * 3 + 2];

  float accX[16], accY[16], accZ[16], accS[16];
#pragma unroll
  for (int q = 0; q < 16; ++q) { accX[q] = 0.f; accY[q] = 0.f; accZ[q] = 0.f; accS[q] = 0.f; }

  const bfh* xb = xTg + (size_t)b * 32768 + hi * 256 + l31 * 8;
  bf16x8 bcur[8], bnxt[8];
#pragma unroll
  for (int kk = 0; kk < 8; ++kk)
    bcur[kk] = *(const bf16x8*)(xb + (size_t)(dh * 4) * 4096 + kk * 512);

#pragma unroll
  for (int dt = 0; dt < 4; ++dt) {
    const int dtg = dh * 4 + dt;
    if (dt < 3) {
#pragma unroll
      for (int kk = 0; kk < 8; ++kk)
        bnxt[kk] = *(const bf16x8*)(xb + (size_t)(dtg + 1) * 4096 + kk * 512);
    }
    f32x16 acc;
#pragma unroll
    for (int q = 0; q < 16; ++q) acc[q] = 0.f;
#pragma unroll
    for (int kk = 0; kk < 8; ++kk)
      acc = __builtin_amdgcn_mfma_f32_32x32x16_bf16(afr[kk], bcur[kk], acc, 0, 0, 0);
    const int d = dtg * 32 + l31;
    const float dx = bax0 - bbs[d * 3 + 0];
    const float dy = bax1 - bbs[d * 3 + 1];
    const float dz = bax2 - bbs[d * 3 + 2];
    float p[16];
#pragma unroll
    for (int q = 0; q < 16; ++q) p[q] = EXP2(acc[q]);
    const float s0 = (p[0] + p[1]) + (p[2] + p[3]);
    const float s1 = (p[4] + p[5]) + (p[6] + p[7]);
    const float s2 = (p[8] + p[9]) + (p[10] + p[11]);
    const float s3 = (p[12] + p[13]) + (p[14] + p[15]);
    const float S = (s0 + s1) + (s2 + s3);
    const float inv = __builtin_amdgcn_rcpf(S);
    const float dxn = dx * inv, dyn = dy * inv, dzn = dz * inv;
#pragma unroll
    for (int q = 0; q < 16; ++q) {
      accS[q] = fmaf(p[q], inv, accS[q]);
      accX[q] = fmaf(p[q], dxn, accX[q]);
      accY[q] = fmaf(p[q], dyn, accY[q]);
      accZ[q] = fmaf(p[q], dzn, accZ[q]);
    }
#pragma unroll
    for (int kk = 0; kk < 8; ++kk) bcur[kk] = bnxt[kk];
  }

  float vk[3] = {0.f, 0.f, 0.f};
#pragma unroll
  for (int c = 0; c < 16; ++c) {
#pragma unroll
    for (int k = 0; k < 3; ++k) {
      const float* w2 = t2w + (k * C_ + c) * 3;
      vk[k] += w2[0] * accX[c] + w2[1] * accY[c] + w2[2] * accZ[c] +
               t2b[k * C_ + c] * accS[c];
    }
  }
#pragma unroll
  for (int m = 1; m <= 16; m <<= 1) {
    vk[0] += __shfl_xor(vk[0], m);
    vk[1] += __shfl_xor(vk[1], m);
    vk[2] += __shfl_xor(vk[2], m);
  }
  if (l31 == 0) {
#pragma unroll
    for (int k = 0; k < 3; ++k)
      vkp[(((size_t)b * 2 + dh) * L_ + aglob) * 3 + k] = vk[k];
  }
}

// ---------------- mse over frames (combines vd partials on the fly) ----------------
__global__ void k_mse(const float* __restrict__ vkp, const float* __restrict__ bb,
                      float* __restrict__ out) {
  const int b = blockIdx.x;   // 0..B-2
  const int t = threadIdx.x;  // 256 == L
  const int bp1 = b + 1;
  float v = 0.f;
#pragma unroll
  for (int k = 0; k < 3; ++k) {
    float vd = vkp[(((size_t)bp1 * 2 + 0) * L_ + t) * 3 + k] +
               vkp[(((size_t)bp1 * 2 + 1) * L_ + t) * 3 + k];
    float nb = bb[((size_t)bp1 * L_ + t) * 3 + k] + STEP_ * vd;
    float d = nb - bb[((size_t)b * L_ + t) * 3 + k];
    v += d * d;
  }
  for (int o = 32; o > 0; o >>= 1) v += __shfl_down(v, o);
  __shared__ float wsum[4];
  if ((t & 63) == 0) wsum[t >> 6] = v;
  __syncthreads();
  if (t == 0) out[b] = (wsum[0] + wsum[1] + wsum[2] + wsum[3]) * (1.0f / L_);
}

extern "C" void kernel_launch(void* const* d_in, const int* in_sizes, int n_in,
                              void* d_out, int out_size, void* d_ws, size_t ws_size,
                              hipStream_t stream) {
  const int* aa = (const int*)d_in[0];
  const float* bb = (const float*)d_in[1];
  const float* emb = (const float*)d_in[2];
  const float* conv_w = (const float*)d_in[3];
  const float* conv_b = (const float*)d_in[4];
  const float* t1w = (const float*)d_in[5];
  const float* t1b = (const float*)d_in[6];
  const float* t2w = (const float*)d_in[7];
  const float* t2b = (const float*)d_in[8];
  float* out = (float*)d_out;

  char* ws = (char*)d_ws;
  bfh* xTg = (bfh*)(ws + 4194304);              // 4 MB frag-layout x
  bfh* t1wb = (bfh*)(ws + 8388608);             // 512 KB
  bfh* wT = (bfh*)(ws + 8912896);               // 640 KB
  float* vkp = (float*)(ws + 9568256);          // 384 KB vd partials
  bfh* x2g = (bfh*)(ws + 10485760);             // 32 or 64 MB frag-layout x2

  const int NPREP = NL_ * K_ * E_ * E_ + 2048 * 128;
  k_prep<<<(NPREP + 255) / 256, 256, 0, stream>>>(conv_w, t1w, wT, t1wb);

  // fused conv stack: embed + 4 layers -> xTg (frag layout), one launch
  k_conv4<<<dim3(L_ / 32, B_), 512, 0, stream>>>(aa, emb, wT, conv_b, xTg);

  const size_t need1 = 10485760ull + 67108864ull;
  if (ws_size >= need1) {
    k_x2<<<B_ * 8, 512, 0, stream>>>(xTg, t1wb, t1b, x2g, 0);
    k_pair<<<B_ * 32, 512, 0, stream>>>(xTg, bb, x2g, t2w, t2b, vkp, 0);
  } else {
    for (int pass = 0; pass < 2; ++pass) {
      const int bBase = pass * 32;
      k_x2<<<32 * 8, 512, 0, stream>>>(xTg, t1wb, t1b, x2g, bBase);
      k_pair<<<32 * 32, 512, 0, stream>>>(xTg, bb, x2g, t2w, t2b, vkp, bBase);
    }
  }

  k_mse<<<B_ - 1, 256, 0, stream>>>(vkp, bb, out);
}

// Round 14
// 153.373 us; speedup vs baseline: 1.1639x; 1.1639x over previous
//
#include <hip/hip_runtime.h>

#define B_ 64
#define L_ 256
#define E_ 128
#define C_ 16
#define K_ 5
#define NL_ 4
#define STEP_ 0.1f
#define LOG2E_ 1.4426950408889634f

typedef __bf16 bfh;
typedef __attribute__((ext_vector_type(8))) __bf16 bf16x8;
typedef __attribute__((ext_vector_type(4))) float f32x4;
typedef __attribute__((ext_vector_type(16))) float f32x16;

#define SWZ(r) (((r) ^ ((r) >> 4)) & 15)

#if __has_builtin(__builtin_amdgcn_exp2f)
#define EXP2(x) __builtin_amdgcn_exp2f(x)
#else
static __device__ __forceinline__ float EXP2(float x) {
  float r;
  asm("v_exp_f32 %0, %1\n\ts_nop 0" : "=v"(r) : "v"(x));
  return r;
}
#endif

// ---------------- merged prep: conv weights -> wT[lay][k][o][i]; t1w -> bf16*log2e ----------------
__global__ void k_prep(const float* __restrict__ w, const float* __restrict__ t1w,
                       bfh* __restrict__ wT, bfh* __restrict__ t1wb) {
  int i = blockIdx.x * 256 + threadIdx.x;
  const int NW = NL_ * K_ * E_ * E_;
  if (i < NW) {
    int ii = i & 127;
    int rest = i >> 7;
    int o = rest & 127;
    int rest2 = rest >> 7;
    int k = rest2 % K_;
    int lay = rest2 / K_;
    wT[i] = (bfh)w[(((size_t)lay * E_ + o) * E_ + ii) * K_ + k];
    return;
  }
  int j = i - NW;
  if (j < 2048 * 128) t1wb[j] = (bfh)(t1w[j] * LOG2E_);
}

// ======== conv common: 16-l-row tiles, 1024 blocks, wave = one 16-o tile, dual chains ========
// staged rows: lb-2 .. lb+17 (20 rows), zeros outside frame.

// ---------------- conv layer 0: embedding gather fused ----------------
__global__ __launch_bounds__(512, 4) void k_conv0(const int* __restrict__ aa,
                                                  const float* __restrict__ emb,
                                                  const bfh* __restrict__ wT,
                                                  const float* __restrict__ bias,
                                                  bfh* __restrict__ xout) {
  __shared__ __align__(16) char hs[20 * 256];
  const int b = blockIdx.y;
  const int lb = blockIdx.x * 16;
  const int t = threadIdx.x;

  if (t < 20 * 16) {
    int row = t >> 4, ch = t & 15;
    int lp = lb + row - 2;
    uint4 pk = {0, 0, 0, 0};
    if (lp >= 0 && lp < L_) {
      int idx = aa[b * L_ + lp];
      float4 f0 = *(const float4*)(emb + (size_t)idx * E_ + ch * 8);
      float4 f1 = *(const float4*)(emb + (size_t)idx * E_ + ch * 8 + 4);
      union { bfh h[8]; uint4 u; } cv;
      cv.h[0] = (bfh)f0.x; cv.h[1] = (bfh)f0.y; cv.h[2] = (bfh)f0.z; cv.h[3] = (bfh)f0.w;
      cv.h[4] = (bfh)f1.x; cv.h[5] = (bfh)f1.y; cv.h[6] = (bfh)f1.z; cv.h[7] = (bfh)f1.w;
      pk = cv.u;
    }
    *(uint4*)(hs + row * 256 + ((ch ^ (row & 7)) << 4)) = pk;
  }
  __syncthreads();

  const int wv = t >> 6, lane = t & 63;
  const int c16 = lane & 15, kg = lane >> 4;
  const int o = wv * 16 + c16;

  f32x4 acc0 = {0.f, 0.f, 0.f, 0.f};
  f32x4 acc1 = {0.f, 0.f, 0.f, 0.f};
#pragma unroll
  for (int k = 0; k < K_; ++k) {
    const bfh* bp = wT + ((size_t)(k * E_ + o)) * E_ + kg * 8;
    bf16x8 b0 = *(const bf16x8*)(bp);
    bf16x8 b1 = *(const bf16x8*)(bp + 32);
    bf16x8 b2 = *(const bf16x8*)(bp + 64);
    bf16x8 b3 = *(const bf16x8*)(bp + 96);
    const int row = c16 + k;
    bf16x8 a0 = *(const bf16x8*)(hs + row * 256 + (((0 * 4 + kg) ^ (row & 7)) << 4));
    bf16x8 a1 = *(const bf16x8*)(hs + row * 256 + (((1 * 4 + kg) ^ (row & 7)) << 4));
    bf16x8 a2 = *(const bf16x8*)(hs + row * 256 + (((2 * 4 + kg) ^ (row & 7)) << 4));
    bf16x8 a3 = *(const bf16x8*)(hs + row * 256 + (((3 * 4 + kg) ^ (row & 7)) << 4));
    acc0 = __builtin_amdgcn_mfma_f32_16x16x32_bf16(a0, b0, acc0, 0, 0, 0);
    acc1 = __builtin_amdgcn_mfma_f32_16x16x32_bf16(a1, b1, acc1, 0, 0, 0);
    acc0 = __builtin_amdgcn_mfma_f32_16x16x32_bf16(a2, b2, acc0, 0, 0, 0);
    acc1 = __builtin_amdgcn_mfma_f32_16x16x32_bf16(a3, b3, acc1, 0, 0, 0);
  }
  const float bo = bias[o];
#pragma unroll
  for (int r = 0; r < 4; ++r) {
    int lrow = kg * 4 + r;
    int srow = lrow + 2;
    float res = (float)*(const bfh*)(hs + srow * 256 +
                                     (((o >> 3) ^ (srow & 7)) << 4) + (o & 7) * 2);
    float v = acc0[r] + acc1[r] + res + bo;
    float ex = EXP2(2.f * LOG2E_ * v);
    float th = 1.f - 2.f / (ex + 1.f);
    xout[((size_t)b * L_ + lb + lrow) * E_ + o] = (bfh)th;
  }
}

// ---------------- conv layers 1..2, row-major out ----------------
__global__ __launch_bounds__(512, 4) void k_conv(const bfh* __restrict__ xin,
                                                 const bfh* __restrict__ wT,
                                                 const float* __restrict__ bias,
                                                 bfh* __restrict__ xout) {
  __shared__ __align__(16) char hs[20 * 256];
  const int b = blockIdx.y;
  const int lb = blockIdx.x * 16;
  const int t = threadIdx.x;

  if (t < 20 * 16) {
    int row = t >> 4, ch = t & 15;
    int lp = lb + row - 2;
    uint4 z = {0, 0, 0, 0};
    uint4 v = (lp >= 0 && lp < L_)
                  ? *(const uint4*)(xin + ((size_t)b * L_ + lp) * E_ + ch * 8)
                  : z;
    *(uint4*)(hs + row * 256 + ((ch ^ (row & 7)) << 4)) = v;
  }
  __syncthreads();

  const int wv = t >> 6, lane = t & 63;
  const int c16 = lane & 15, kg = lane >> 4;
  const int o = wv * 16 + c16;

  f32x4 acc0 = {0.f, 0.f, 0.f, 0.f};
  f32x4 acc1 = {0.f, 0.f, 0.f, 0.f};
#pragma unroll
  for (int k = 0; k < K_; ++k) {
    const bfh* bp = wT + ((size_t)(k * E_ + o)) * E_ + kg * 8;
    bf16x8 b0 = *(const bf16x8*)(bp);
    bf16x8 b1 = *(const bf16x8*)(bp + 32);
    bf16x8 b2 = *(const bf16x8*)(bp + 64);
    bf16x8 b3 = *(const bf16x8*)(bp + 96);
    const int row = c16 + k;
    bf16x8 a0 = *(const bf16x8*)(hs + row * 256 + (((0 * 4 + kg) ^ (row & 7)) << 4));
    bf16x8 a1 = *(const bf16x8*)(hs + row * 256 + (((1 * 4 + kg) ^ (row & 7)) << 4));
    bf16x8 a2 = *(const bf16x8*)(hs + row * 256 + (((2 * 4 + kg) ^ (row & 7)) << 4));
    bf16x8 a3 = *(const bf16x8*)(hs + row * 256 + (((3 * 4 + kg) ^ (row & 7)) << 4));
    acc0 = __builtin_amdgcn_mfma_f32_16x16x32_bf16(a0, b0, acc0, 0, 0, 0);
    acc1 = __builtin_amdgcn_mfma_f32_16x16x32_bf16(a1, b1, acc1, 0, 0, 0);
    acc0 = __builtin_amdgcn_mfma_f32_16x16x32_bf16(a2, b2, acc0, 0, 0, 0);
    acc1 = __builtin_amdgcn_mfma_f32_16x16x32_bf16(a3, b3, acc1, 0, 0, 0);
  }
  const float bo = bias[o];
#pragma unroll
  for (int r = 0; r < 4; ++r) {
    int lrow = kg * 4 + r;
    int srow = lrow + 2;
    float res = (float)*(const bfh*)(hs + srow * 256 +
                                     (((o >> 3) ^ (srow & 7)) << 4) + (o & 7) * 2);
    float v = acc0[r] + acc1[r] + res + bo;
    float ex = EXP2(2.f * LOG2E_ * v);
    float th = 1.f - 2.f / (ex + 1.f);
    xout[((size_t)b * L_ + lb + lrow) * E_ + o] = (bfh)th;
  }
}

// ---------------- last conv layer: frag-layout out xTg[b][dt][kk][hi][l31][8] ----------------
__global__ __launch_bounds__(512, 4) void k_conv_last(const bfh* __restrict__ xin,
                                                      const bfh* __restrict__ wT,
                                                      const float* __restrict__ bias,
                                                      bfh* __restrict__ xTg) {
  __shared__ __align__(16) char hs[20 * 256];
  const int b = blockIdx.y;
  const int lb = blockIdx.x * 16;
  const int dt = blockIdx.x >> 1;
  const int half = blockIdx.x & 1;
  const int t = threadIdx.x;

  if (t < 20 * 16) {
    int row = t >> 4, ch = t & 15;
    int lp = lb + row - 2;
    uint4 z = {0, 0, 0, 0};
    uint4 v = (lp >= 0 && lp < L_)
                  ? *(const uint4*)(xin + ((size_t)b * L_ + lp) * E_ + ch * 8)
                  : z;
    *(uint4*)(hs + row * 256 + ((ch ^ (row & 7)) << 4)) = v;
  }
  __syncthreads();

  const int wv = t >> 6, lane = t & 63;
  const int c16 = lane & 15, kg = lane >> 4;
  const int o = wv * 16 + c16;

  f32x4 acc0 = {0.f, 0.f, 0.f, 0.f};
  f32x4 acc1 = {0.f, 0.f, 0.f, 0.f};
#pragma unroll
  for (int k = 0; k < K_; ++k) {
    const bfh* bp = wT + ((size_t)(k * E_ + o)) * E_ + kg * 8;
    bf16x8 b0 = *(const bf16x8*)(bp);
    bf16x8 b1 = *(const bf16x8*)(bp + 32);
    bf16x8 b2 = *(const bf16x8*)(bp + 64);
    bf16x8 b3 = *(const bf16x8*)(bp + 96);
    const int row = c16 + k;
    bf16x8 a0 = *(const bf16x8*)(hs + row * 256 + (((0 * 4 + kg) ^ (row & 7)) << 4));
    bf16x8 a1 = *(const bf16x8*)(hs + row * 256 + (((1 * 4 + kg) ^ (row & 7)) << 4));
    bf16x8 a2 = *(const bf16x8*)(hs + row * 256 + (((2 * 4 + kg) ^ (row & 7)) << 4));
    bf16x8 a3 = *(const bf16x8*)(hs + row * 256 + (((3 * 4 + kg) ^ (row & 7)) << 4));
    acc0 = __builtin_amdgcn_mfma_f32_16x16x32_bf16(a0, b0, acc0, 0, 0, 0);
    acc1 = __builtin_amdgcn_mfma_f32_16x16x32_bf16(a1, b1, acc1, 0, 0, 0);
    acc0 = __builtin_amdgcn_mfma_f32_16x16x32_bf16(a2, b2, acc0, 0, 0, 0);
    acc1 = __builtin_amdgcn_mfma_f32_16x16x32_bf16(a3, b3, acc1, 0, 0, 0);
  }
  const float bo = bias[o];
  const int kkp = o >> 4;        // == wv
  const int hic = (o >> 3) & 1;
  const int e7 = o & 7;
#pragma unroll
  for (int r = 0; r < 4; ++r) {
    int lrow = kg * 4 + r;
    int srow = lrow + 2;
    float res = (float)*(const bfh*)(hs + srow * 256 +
                                     (((o >> 3) ^ (srow & 7)) << 4) + (o & 7) * 2);
    float v = acc0[r] + acc1[r] + res + bo;
    float ex = EXP2(2.f * LOG2E_ * v);
    float th = 1.f - 2.f / (ex + 1.f);
    int l31 = half * 16 + lrow;
    size_t el = ((((size_t)b * 8 + dt) * 8 + kkp) * 2 + hic) * 256 + l31 * 8 + e7;
    xTg[el] = (bfh)th;
  }
}

// ---------------- x2 GEMM: x2g[b_loc][apair 128][echunk 16][m32 32][8 bf16], frag-ready ----------------
__global__ __launch_bounds__(512, 2) void k_x2(const bfh* __restrict__ xTg,
                                               const bfh* __restrict__ t1wb,
                                               const float* __restrict__ t1b,
                                               bfh* __restrict__ x2g,
                                               int bBase) {
  __shared__ __align__(16) char smem[65536 + 2 * 8192];
  char* XF = smem;
  const unsigned u = blockIdx.x;
  const int xcd = u & 7;
  const int g = u >> 3;
  const int b_loc = xcd + 8 * (g >> 3);
  const int ne = g & 7;
  const int b = bBase + b_loc;
  const int t = threadIdx.x;
  const int wv = t >> 6, lane = t & 63;
  const int c16 = lane & 15, kg = lane >> 4;

#pragma unroll
  for (int i = 0; i < 8; ++i) {
    int c = t + i * 512;
    int l31 = c & 31, hi5 = (c >> 5) & 1, kk = (c >> 6) & 7, dt = c >> 9;
    int row = dt * 32 + l31;
    int ch = (kk * 2 + hi5) ^ SWZ(row);
    *(uint4*)(XF + row * 256 + (ch << 4)) =
        *(const uint4*)(xTg + (size_t)b * 32768 + (size_t)c * 8);
  }
  __syncthreads();

  bf16x8 bf[2][4];
  float bias[2];
#pragma unroll
  for (int j = 0; j < 2; ++j) {
    const int e = ne * 16 + wv * 2 + j;
    const int n = e * 16 + c16;
#pragma unroll
    for (int kk = 0; kk < 4; ++kk)
      bf[j][kk] = *(const bf16x8*)(t1wb + (size_t)n * 128 + kk * 32 + kg * 8);
    bias[j] = t1b[n] * LOG2E_;
  }

#pragma unroll 1
  for (int st = 0; st < 16; ++st) {
    char* sc = smem + 65536 + (st & 1) * 8192;
    bf16x8 a1[4];
    const int rowa = st * 16 + c16;
#pragma unroll
    for (int kk = 0; kk < 4; ++kk)
      a1[kk] = *(const bf16x8*)(XF + rowa * 256 + (((kk * 4 + kg) ^ SWZ(rowa)) << 4));
    f32x4 acc0 = {0.f, 0.f, 0.f, 0.f};
    f32x4 acc1 = {0.f, 0.f, 0.f, 0.f};
#pragma unroll
    for (int kk = 0; kk < 4; ++kk) {
      acc0 = __builtin_amdgcn_mfma_f32_16x16x32_bf16(a1[kk], bf[0][kk], acc0, 0, 0, 0);
      acc1 = __builtin_amdgcn_mfma_f32_16x16x32_bf16(a1[kk], bf[1][kk], acc1, 0, 0, 0);
    }
#pragma unroll
    for (int r = 0; r < 4; ++r) {
      int a = kg * 4 + r;
      int m5 = (c16 & 3) | ((a & 1) << 2) | ((c16 >> 2) << 3);
      int row = (a >> 1) * 32 + m5;
      union { bfh h; ushort s; } lo, hi2;
      lo.h = (bfh)(acc0[r] + bias[0]);
      hi2.h = (bfh)(acc1[r] + bias[1]);
      unsigned pk = (unsigned)lo.s | ((unsigned)hi2.s << 16);
      *(unsigned*)(sc + row * 32 + (((wv) ^ ((row >> 2) & 7)) << 2)) = pk;
    }
    __syncthreads();
    {
      const int m32 = t & 31;
      const int eo = (t >> 5) & 1;
      const int mb = t >> 6;
      const int row = mb * 32 + m32;
      uint4 v;
      unsigned* vp = (unsigned*)&v;
#pragma unroll
      for (int jj = 0; jj < 4; ++jj) {
        int j2 = eo * 4 + jj;
        vp[jj] = *(const unsigned*)(sc + row * 32 + ((j2 ^ ((row >> 2) & 7)) << 2));
      }
      size_t el = (((size_t)(b_loc * 128 + st * 8 + mb)) * 16 + ne * 2 + eo) * 256 + m32 * 8;
      *(uint4*)(x2g + el) = v;
    }
  }
}

// ---------------- pairwise kernel: 512 thr, single-acc chain, native exp2 ----------------
__global__ __launch_bounds__(512, 2) void k_pair(
    const bfh* __restrict__ xTg,
    const float* __restrict__ bb,
    const bfh* __restrict__ x2g,
    const float* __restrict__ t2w,
    const float* __restrict__ t2b,
    float* __restrict__ vkp,       // [b][dh][a][3] f32
    int bBase) {
  __shared__ __align__(16) float bbs[L_ * 3];
  const int t = threadIdx.x;
  const unsigned u = blockIdx.x;
  const int b_loc = (u & 7) | ((u >> 8) << 3);
  const int inner = (u >> 3) & 31;
  const int atile = inner >> 1;
  const int dh = inner & 1;
  const int b = bBase + b_loc;
  const int lane = t & 63;
  const int wv = t >> 6;
  const int l31 = lane & 31;
  const int hi = lane >> 5;

  if (t < 192) ((float4*)bbs)[t] = ((const float4*)(bb + b * (L_ * 3)))[t];
  __syncthreads();

  bf16x8 afr[8];
  const bfh* abase = x2g + ((size_t)(b_loc * 128 + atile * 8 + wv)) * 4096 + l31 * 8;
#pragma unroll
  for (int kk = 0; kk < 8; ++kk)
    afr[kk] = *(const bf16x8*)(abase + (kk * 2 + hi) * 256);

  const int aglob = atile * 16 + 2 * wv + hi;
  const float bax0 = bbs[aglob * 3 + 0];
  const float bax1 = bbs[aglob * 3 + 1];
  const float bax2 = bbs[aglob * 3 + 2];

  float accX[16], accY[16], accZ[16], accS[16];
#pragma unroll
  for (int q = 0; q < 16; ++q) { accX[q] = 0.f; accY[q] = 0.f; accZ[q] = 0.f; accS[q] = 0.f; }

  const bfh* xb = xTg + (size_t)b * 32768 + hi * 256 + l31 * 8;
  bf16x8 bcur[8], bnxt[8];
#pragma unroll
  for (int kk = 0; kk < 8; ++kk)
    bcur[kk] = *(const bf16x8*)(xb + (size_t)(dh * 4) * 4096 + kk * 512);

#pragma unroll
  for (int dt = 0; dt < 4; ++dt) {
    const int dtg = dh * 4 + dt;
    if (dt < 3) {
#pragma unroll
      for (int kk = 0; kk < 8; ++kk)
        bnxt[kk] = *(const bf16x8*)(xb + (size_t)(dtg + 1) * 4096 + kk * 512);
    }
    f32x16 acc;
#pragma unroll
    for (int q = 0; q < 16; ++q) acc[q] = 0.f;
#pragma unroll
    for (int kk = 0; kk < 8; ++kk)
      acc = __builtin_amdgcn_mfma_f32_32x32x16_bf16(afr[kk], bcur[kk], acc, 0, 0, 0);
    const int d = dtg * 32 + l31;
    const float dx = bax0 - bbs[d * 3 + 0];
    const float dy = bax1 - bbs[d * 3 + 1];
    const float dz = bax2 - bbs[d * 3 + 2];
    float p[16];
#pragma unroll
    for (int q = 0; q < 16; ++q) p[q] = EXP2(acc[q]);
    const float s0 = (p[0] + p[1]) + (p[2] + p[3]);
    const float s1 = (p[4] + p[5]) + (p[6] + p[7]);
    const float s2 = (p[8] + p[9]) + (p[10] + p[11]);
    const float s3 = (p[12] + p[13]) + (p[14] + p[15]);
    const float S = (s0 + s1) + (s2 + s3);
    const float inv = __builtin_amdgcn_rcpf(S);
    const float dxn = dx * inv, dyn = dy * inv, dzn = dz * inv;
#pragma unroll
    for (int q = 0; q < 16; ++q) {
      accS[q] = fmaf(p[q], inv, accS[q]);
      accX[q] = fmaf(p[q], dxn, accX[q]);
      accY[q] = fmaf(p[q], dyn, accY[q]);
      accZ[q] = fmaf(p[q], dzn, accZ[q]);
    }
#pragma unroll
    for (int kk = 0; kk < 8; ++kk) bcur[kk] = bnxt[kk];
  }

  float vk[3] = {0.f, 0.f, 0.f};
#pragma unroll
  for (int c = 0; c < 16; ++c) {
#pragma unroll
    for (int k = 0; k < 3; ++k) {
      const float* w2 = t2w + (k * C_ + c) * 3;
      vk[k] += w2[0] * accX[c] + w2[1] * accY[c] + w2[2] * accZ[c] +
               t2b[k * C_ + c] * accS[c];
    }
  }
#pragma unroll
  for (int m = 1; m <= 16; m <<= 1) {
    vk[0] += __shfl_xor(vk[0], m);
    vk[1] += __shfl_xor(vk[1], m);
    vk[2] += __shfl_xor(vk[2], m);
  }
  if (l31 == 0) {
#pragma unroll
    for (int k = 0; k < 3; ++k)
      vkp[(((size_t)b * 2 + dh) * L_ + aglob) * 3 + k] = vk[k];
  }
}

// ---------------- mse over frames (combines vd partials on the fly) ----------------
__global__ void k_mse(const float* __restrict__ vkp, const float* __restrict__ bb,
                      float* __restrict__ out) {
  const int b = blockIdx.x;
  const int t = threadIdx.x;
  const int bp1 = b + 1;
  float v = 0.f;
#pragma unroll
  for (int k = 0; k < 3; ++k) {
    float vd = vkp[(((size_t)bp1 * 2 + 0) * L_ + t) * 3 + k] +
               vkp[(((size_t)bp1 * 2 + 1) * L_ + t) * 3 + k];
    float nb = bb[((size_t)bp1 * L_ + t) * 3 + k] + STEP_ * vd;
    float d = nb - bb[((size_t)b * L_ + t) * 3 + k];
    v += d * d;
  }
  for (int o = 32; o > 0; o >>= 1) v += __shfl_down(v, o);
  __shared__ float wsum[4];
  if ((t & 63) == 0) wsum[t >> 6] = v;
  __syncthreads();
  if (t == 0) out[b] = (wsum[0] + wsum[1] + wsum[2] + wsum[3]) * (1.0f / L_);
}

extern "C" void kernel_launch(void* const* d_in, const int* in_sizes, int n_in,
                              void* d_out, int out_size, void* d_ws, size_t ws_size,
                              hipStream_t stream) {
  const int* aa = (const int*)d_in[0];
  const float* bb = (const float*)d_in[1];
  const float* emb = (const float*)d_in[2];
  const float* conv_w = (const float*)d_in[3];
  const float* conv_b = (const float*)d_in[4];
  const float* t1w = (const float*)d_in[5];
  const float* t1b = (const float*)d_in[6];
  const float* t2w = (const float*)d_in[7];
  const float* t2b = (const float*)d_in[8];
  float* out = (float*)d_out;

  char* ws = (char*)d_ws;
  bfh* xA = (bfh*)ws;                           // 4 MB row-major intermediate
  bfh* xTg = (bfh*)(ws + 4194304);              // 4 MB frag-layout x
  bfh* t1wb = (bfh*)(ws + 8388608);             // 512 KB
  bfh* wT = (bfh*)(ws + 8912896);               // 640 KB
  float* vkp = (float*)(ws + 9568256);          // 384 KB vd partials
  bfh* x2g = (bfh*)(ws + 10485760);             // 32 or 64 MB frag-layout x2
  bfh* xB = (bfh*)(ws + 10485760);              // aliases x2g (dead before k_x2)

  const int NPREP = NL_ * K_ * E_ * E_ + 2048 * 128;
  k_prep<<<(NPREP + 255) / 256, 256, 0, stream>>>(conv_w, t1w, wT, t1wb);

  // conv stack: emb -> xB -> xA -> xB -> xTg (frag layout), 16-row tiles
  k_conv0<<<dim3(L_ / 16, B_), 512, 0, stream>>>(aa, emb, wT, conv_b, xB);
  k_conv<<<dim3(L_ / 16, B_), 512, 0, stream>>>(xB, wT + (size_t)1 * K_ * E_ * E_,
                                                conv_b + 1 * E_, xA);
  k_conv<<<dim3(L_ / 16, B_), 512, 0, stream>>>(xA, wT + (size_t)2 * K_ * E_ * E_,
                                                conv_b + 2 * E_, xB);
  k_conv_last<<<dim3(L_ / 16, B_), 512, 0, stream>>>(xB, wT + (size_t)3 * K_ * E_ * E_,
                                                     conv_b + 3 * E_, xTg);

  const size_t need1 = 10485760ull + 67108864ull;
  if (ws_size >= need1) {
    k_x2<<<B_ * 8, 512, 0, stream>>>(xTg, t1wb, t1b, x2g, 0);
    k_pair<<<B_ * 32, 512, 0, stream>>>(xTg, bb, x2g, t2w, t2b, vkp, 0);
  } else {
    for (int pass = 0; pass < 2; ++pass) {
      const int bBase = pass * 32;
      k_x2<<<32 * 8, 512, 0, stream>>>(xTg, t1wb, t1b, x2g, bBase);
      k_pair<<<32 * 32, 512, 0, stream>>>(xTg, bb, x2g, t2w, t2b, vkp, bBase);
    }
  }

  k_mse<<<B_ - 1, 256, 0, stream>>>(vkp, bb, out);
}

// Round 15
// 144.306 us; speedup vs baseline: 1.2370x; 1.0628x over previous
//
#include <hip/hip_runtime.h>

#define B_ 64
#define L_ 256
#define E_ 128
#define C_ 16
#define K_ 5
#define NL_ 4
#define STEP_ 0.1f
#define LOG2E_ 1.4426950408889634f

typedef __bf16 bfh;
typedef __attribute__((ext_vector_type(8))) __bf16 bf16x8;
typedef __attribute__((ext_vector_type(4))) float f32x4;
typedef __attribute__((ext_vector_type(16))) float f32x16;

#define SWZ(r) (((r) ^ ((r) >> 4)) & 15)

#if __has_builtin(__builtin_amdgcn_exp2f)
#define EXP2(x) __builtin_amdgcn_exp2f(x)
#else
static __device__ __forceinline__ float EXP2(float x) {
  float r;
  asm("v_exp_f32 %0, %1\n\ts_nop 0" : "=v"(r) : "v"(x));
  return r;
}
#endif

// ---------------- merged prep: conv weights -> wT[lay][k][o][i]; t1w -> bf16*log2e ----------------
__global__ void k_prep(const float* __restrict__ w, const float* __restrict__ t1w,
                       bfh* __restrict__ wT, bfh* __restrict__ t1wb) {
  int i = blockIdx.x * 256 + threadIdx.x;
  const int NW = NL_ * K_ * E_ * E_;
  if (i < NW) {
    int ii = i & 127;
    int rest = i >> 7;
    int o = rest & 127;
    int rest2 = rest >> 7;
    int k = rest2 % K_;
    int lay = rest2 / K_;
    wT[i] = (bfh)w[(((size_t)lay * E_ + o) * E_ + ii) * K_ + k];
    return;
  }
  int j = i - NW;
  if (j < 2048 * 128) t1wb[j] = (bfh)(t1w[j] * LOG2E_);
}

// ======== conv common: 16-l-row tiles, 1024 blocks, wave = one 16-o tile, dual chains ========

// ---------------- conv layer 0: embedding gather fused ----------------
__global__ __launch_bounds__(512, 4) void k_conv0(const int* __restrict__ aa,
                                                  const float* __restrict__ emb,
                                                  const bfh* __restrict__ wT,
                                                  const float* __restrict__ bias,
                                                  bfh* __restrict__ xout) {
  __shared__ __align__(16) char hs[20 * 256];
  const int b = blockIdx.y;
  const int lb = blockIdx.x * 16;
  const int t = threadIdx.x;

  if (t < 20 * 16) {
    int row = t >> 4, ch = t & 15;
    int lp = lb + row - 2;
    uint4 pk = {0, 0, 0, 0};
    if (lp >= 0 && lp < L_) {
      int idx = aa[b * L_ + lp];
      float4 f0 = *(const float4*)(emb + (size_t)idx * E_ + ch * 8);
      float4 f1 = *(const float4*)(emb + (size_t)idx * E_ + ch * 8 + 4);
      union { bfh h[8]; uint4 u; } cv;
      cv.h[0] = (bfh)f0.x; cv.h[1] = (bfh)f0.y; cv.h[2] = (bfh)f0.z; cv.h[3] = (bfh)f0.w;
      cv.h[4] = (bfh)f1.x; cv.h[5] = (bfh)f1.y; cv.h[6] = (bfh)f1.z; cv.h[7] = (bfh)f1.w;
      pk = cv.u;
    }
    *(uint4*)(hs + row * 256 + ((ch ^ (row & 7)) << 4)) = pk;
  }
  __syncthreads();

  const int wv = t >> 6, lane = t & 63;
  const int c16 = lane & 15, kg = lane >> 4;
  const int o = wv * 16 + c16;

  f32x4 acc0 = {0.f, 0.f, 0.f, 0.f};
  f32x4 acc1 = {0.f, 0.f, 0.f, 0.f};
#pragma unroll
  for (int k = 0; k < K_; ++k) {
    const bfh* bp = wT + ((size_t)(k * E_ + o)) * E_ + kg * 8;
    bf16x8 b0 = *(const bf16x8*)(bp);
    bf16x8 b1 = *(const bf16x8*)(bp + 32);
    bf16x8 b2 = *(const bf16x8*)(bp + 64);
    bf16x8 b3 = *(const bf16x8*)(bp + 96);
    const int row = c16 + k;
    bf16x8 a0 = *(const bf16x8*)(hs + row * 256 + (((0 * 4 + kg) ^ (row & 7)) << 4));
    bf16x8 a1 = *(const bf16x8*)(hs + row * 256 + (((1 * 4 + kg) ^ (row & 7)) << 4));
    bf16x8 a2 = *(const bf16x8*)(hs + row * 256 + (((2 * 4 + kg) ^ (row & 7)) << 4));
    bf16x8 a3 = *(const bf16x8*)(hs + row * 256 + (((3 * 4 + kg) ^ (row & 7)) << 4));
    acc0 = __builtin_amdgcn_mfma_f32_16x16x32_bf16(a0, b0, acc0, 0, 0, 0);
    acc1 = __builtin_amdgcn_mfma_f32_16x16x32_bf16(a1, b1, acc1, 0, 0, 0);
    acc0 = __builtin_amdgcn_mfma_f32_16x16x32_bf16(a2, b2, acc0, 0, 0, 0);
    acc1 = __builtin_amdgcn_mfma_f32_16x16x32_bf16(a3, b3, acc1, 0, 0, 0);
  }
  const float bo = bias[o];
#pragma unroll
  for (int r = 0; r < 4; ++r) {
    int lrow = kg * 4 + r;
    int srow = lrow + 2;
    float res = (float)*(const bfh*)(hs + srow * 256 +
                                     (((o >> 3) ^ (srow & 7)) << 4) + (o & 7) * 2);
    float v = acc0[r] + acc1[r] + res + bo;
    float ex = EXP2(2.f * LOG2E_ * v);
    float th = 1.f - 2.f / (ex + 1.f);
    xout[((size_t)b * L_ + lb + lrow) * E_ + o] = (bfh)th;
  }
}

// ---------------- conv layers 1..2, row-major out ----------------
__global__ __launch_bounds__(512, 4) void k_conv(const bfh* __restrict__ xin,
                                                 const bfh* __restrict__ wT,
                                                 const float* __restrict__ bias,
                                                 bfh* __restrict__ xout) {
  __shared__ __align__(16) char hs[20 * 256];
  const int b = blockIdx.y;
  const int lb = blockIdx.x * 16;
  const int t = threadIdx.x;

  if (t < 20 * 16) {
    int row = t >> 4, ch = t & 15;
    int lp = lb + row - 2;
    uint4 z = {0, 0, 0, 0};
    uint4 v = (lp >= 0 && lp < L_)
                  ? *(const uint4*)(xin + ((size_t)b * L_ + lp) * E_ + ch * 8)
                  : z;
    *(uint4*)(hs + row * 256 + ((ch ^ (row & 7)) << 4)) = v;
  }
  __syncthreads();

  const int wv = t >> 6, lane = t & 63;
  const int c16 = lane & 15, kg = lane >> 4;
  const int o = wv * 16 + c16;

  f32x4 acc0 = {0.f, 0.f, 0.f, 0.f};
  f32x4 acc1 = {0.f, 0.f, 0.f, 0.f};
#pragma unroll
  for (int k = 0; k < K_; ++k) {
    const bfh* bp = wT + ((size_t)(k * E_ + o)) * E_ + kg * 8;
    bf16x8 b0 = *(const bf16x8*)(bp);
    bf16x8 b1 = *(const bf16x8*)(bp + 32);
    bf16x8 b2 = *(const bf16x8*)(bp + 64);
    bf16x8 b3 = *(const bf16x8*)(bp + 96);
    const int row = c16 + k;
    bf16x8 a0 = *(const bf16x8*)(hs + row * 256 + (((0 * 4 + kg) ^ (row & 7)) << 4));
    bf16x8 a1 = *(const bf16x8*)(hs + row * 256 + (((1 * 4 + kg) ^ (row & 7)) << 4));
    bf16x8 a2 = *(const bf16x8*)(hs + row * 256 + (((2 * 4 + kg) ^ (row & 7)) << 4));
    bf16x8 a3 = *(const bf16x8*)(hs + row * 256 + (((3 * 4 + kg) ^ (row & 7)) << 4));
    acc0 = __builtin_amdgcn_mfma_f32_16x16x32_bf16(a0, b0, acc0, 0, 0, 0);
    acc1 = __builtin_amdgcn_mfma_f32_16x16x32_bf16(a1, b1, acc1, 0, 0, 0);
    acc0 = __builtin_amdgcn_mfma_f32_16x16x32_bf16(a2, b2, acc0, 0, 0, 0);
    acc1 = __builtin_amdgcn_mfma_f32_16x16x32_bf16(a3, b3, acc1, 0, 0, 0);
  }
  const float bo = bias[o];
#pragma unroll
  for (int r = 0; r < 4; ++r) {
    int lrow = kg * 4 + r;
    int srow = lrow + 2;
    float res = (float)*(const bfh*)(hs + srow * 256 +
                                     (((o >> 3) ^ (srow & 7)) << 4) + (o & 7) * 2);
    float v = acc0[r] + acc1[r] + res + bo;
    float ex = EXP2(2.f * LOG2E_ * v);
    float th = 1.f - 2.f / (ex + 1.f);
    xout[((size_t)b * L_ + lb + lrow) * E_ + o] = (bfh)th;
  }
}

// ---------------- last conv layer: frag-layout out xTg[b][dt][kk][hi][l31][8] ----------------
__global__ __launch_bounds__(512, 4) void k_conv_last(const bfh* __restrict__ xin,
                                                      const bfh* __restrict__ wT,
                                                      const float* __restrict__ bias,
                                                      bfh* __restrict__ xTg) {
  __shared__ __align__(16) char hs[20 * 256];
  const int b = blockIdx.y;
  const int lb = blockIdx.x * 16;
  const int dt = blockIdx.x >> 1;
  const int half = blockIdx.x & 1;
  const int t = threadIdx.x;

  if (t < 20 * 16) {
    int row = t >> 4, ch = t & 15;
    int lp = lb + row - 2;
    uint4 z = {0, 0, 0, 0};
    uint4 v = (lp >= 0 && lp < L_)
                  ? *(const uint4*)(xin + ((size_t)b * L_ + lp) * E_ + ch * 8)
                  : z;
    *(uint4*)(hs + row * 256 + ((ch ^ (row & 7)) << 4)) = v;
  }
  __syncthreads();

  const int wv = t >> 6, lane = t & 63;
  const int c16 = lane & 15, kg = lane >> 4;
  const int o = wv * 16 + c16;

  f32x4 acc0 = {0.f, 0.f, 0.f, 0.f};
  f32x4 acc1 = {0.f, 0.f, 0.f, 0.f};
#pragma unroll
  for (int k = 0; k < K_; ++k) {
    const bfh* bp = wT + ((size_t)(k * E_ + o)) * E_ + kg * 8;
    bf16x8 b0 = *(const bf16x8*)(bp);
    bf16x8 b1 = *(const bf16x8*)(bp + 32);
    bf16x8 b2 = *(const bf16x8*)(bp + 64);
    bf16x8 b3 = *(const bf16x8*)(bp + 96);
    const int row = c16 + k;
    bf16x8 a0 = *(const bf16x8*)(hs + row * 256 + (((0 * 4 + kg) ^ (row & 7)) << 4));
    bf16x8 a1 = *(const bf16x8*)(hs + row * 256 + (((1 * 4 + kg) ^ (row & 7)) << 4));
    bf16x8 a2 = *(const bf16x8*)(hs + row * 256 + (((2 * 4 + kg) ^ (row & 7)) << 4));
    bf16x8 a3 = *(const bf16x8*)(hs + row * 256 + (((3 * 4 + kg) ^ (row & 7)) << 4));
    acc0 = __builtin_amdgcn_mfma_f32_16x16x32_bf16(a0, b0, acc0, 0, 0, 0);
    acc1 = __builtin_amdgcn_mfma_f32_16x16x32_bf16(a1, b1, acc1, 0, 0, 0);
    acc0 = __builtin_amdgcn_mfma_f32_16x16x32_bf16(a2, b2, acc0, 0, 0, 0);
    acc1 = __builtin_amdgcn_mfma_f32_16x16x32_bf16(a3, b3, acc1, 0, 0, 0);
  }
  const float bo = bias[o];
  const int kkp = o >> 4;
  const int hic = (o >> 3) & 1;
  const int e7 = o & 7;
#pragma unroll
  for (int r = 0; r < 4; ++r) {
    int lrow = kg * 4 + r;
    int srow = lrow + 2;
    float res = (float)*(const bfh*)(hs + srow * 256 +
                                     (((o >> 3) ^ (srow & 7)) << 4) + (o & 7) * 2);
    float v = acc0[r] + acc1[r] + res + bo;
    float ex = EXP2(2.f * LOG2E_ * v);
    float th = 1.f - 2.f / (ex + 1.f);
    int l31 = half * 16 + lrow;
    size_t el = ((((size_t)b * 8 + dt) * 8 + kkp) * 2 + hic) * 256 + l31 * 8 + e7;
    xTg[el] = (bfh)th;
  }
}

// ---------------- x2 GEMM: x2g[b_loc][apair 128][echunk 16][m32 32][8 bf16], frag-ready ----------------
__global__ __launch_bounds__(512, 2) void k_x2(const bfh* __restrict__ xTg,
                                               const bfh* __restrict__ t1wb,
                                               const float* __restrict__ t1b,
                                               bfh* __restrict__ x2g,
                                               int bBase) {
  __shared__ __align__(16) char smem[65536 + 2 * 8192];
  char* XF = smem;
  const unsigned u = blockIdx.x;
  const int xcd = u & 7;
  const int g = u >> 3;
  const int b_loc = xcd + 8 * (g >> 3);
  const int ne = g & 7;
  const int b = bBase + b_loc;
  const int t = threadIdx.x;
  const int wv = t >> 6, lane = t & 63;
  const int c16 = lane & 15, kg = lane >> 4;

#pragma unroll
  for (int i = 0; i < 8; ++i) {
    int c = t + i * 512;
    int l31 = c & 31, hi5 = (c >> 5) & 1, kk = (c >> 6) & 7, dt = c >> 9;
    int row = dt * 32 + l31;
    int ch = (kk * 2 + hi5) ^ SWZ(row);
    *(uint4*)(XF + row * 256 + (ch << 4)) =
        *(const uint4*)(xTg + (size_t)b * 32768 + (size_t)c * 8);
  }
  __syncthreads();

  bf16x8 bf[2][4];
  float bias[2];
#pragma unroll
  for (int j = 0; j < 2; ++j) {
    const int e = ne * 16 + wv * 2 + j;
    const int n = e * 16 + c16;
#pragma unroll
    for (int kk = 0; kk < 4; ++kk)
      bf[j][kk] = *(const bf16x8*)(t1wb + (size_t)n * 128 + kk * 32 + kg * 8);
    bias[j] = t1b[n] * LOG2E_;
  }

#pragma unroll 1
  for (int st = 0; st < 16; ++st) {
    char* sc = smem + 65536 + (st & 1) * 8192;
    bf16x8 a1[4];
    const int rowa = st * 16 + c16;
#pragma unroll
    for (int kk = 0; kk < 4; ++kk)
      a1[kk] = *(const bf16x8*)(XF + rowa * 256 + (((kk * 4 + kg) ^ SWZ(rowa)) << 4));
    f32x4 acc0 = {0.f, 0.f, 0.f, 0.f};
    f32x4 acc1 = {0.f, 0.f, 0.f, 0.f};
#pragma unroll
    for (int kk = 0; kk < 4; ++kk) {
      acc0 = __builtin_amdgcn_mfma_f32_16x16x32_bf16(a1[kk], bf[0][kk], acc0, 0, 0, 0);
      acc1 = __builtin_amdgcn_mfma_f32_16x16x32_bf16(a1[kk], bf[1][kk], acc1, 0, 0, 0);
    }
#pragma unroll
    for (int r = 0; r < 4; ++r) {
      int a = kg * 4 + r;
      int m5 = (c16 & 3) | ((a & 1) << 2) | ((c16 >> 2) << 3);
      int row = (a >> 1) * 32 + m5;
      union { bfh h; ushort s; } lo, hi2;
      lo.h = (bfh)(acc0[r] + bias[0]);
      hi2.h = (bfh)(acc1[r] + bias[1]);
      unsigned pk = (unsigned)lo.s | ((unsigned)hi2.s << 16);
      *(unsigned*)(sc + row * 32 + (((wv) ^ ((row >> 2) & 7)) << 2)) = pk;
    }
    __syncthreads();
    {
      const int m32 = t & 31;
      const int eo = (t >> 5) & 1;
      const int mb = t >> 6;
      const int row = mb * 32 + m32;
      uint4 v;
      unsigned* vp = (unsigned*)&v;
#pragma unroll
      for (int jj = 0; jj < 4; ++jj) {
        int j2 = eo * 4 + jj;
        vp[jj] = *(const unsigned*)(sc + row * 32 + ((j2 ^ ((row >> 2) & 7)) << 2));
      }
      size_t el = (((size_t)(b_loc * 128 + st * 8 + mb)) * 16 + ne * 2 + eo) * 256 + m32 * 8;
      *(uint4*)(x2g + el) = v;
    }
  }
}

// ---------------- pairwise kernel: 256 thr (4 waves), 8 a x 128 d per block ----------------
__global__ __launch_bounds__(256, 2) void k_pair(
    const bfh* __restrict__ xTg,
    const float* __restrict__ bb,
    const bfh* __restrict__ x2g,
    const float* __restrict__ t2w,
    const float* __restrict__ t2b,
    float* __restrict__ vkp,       // [b][dh][a][3] f32
    int bBase) {
  __shared__ __align__(16) float bbs[L_ * 3];
  const int t = threadIdx.x;
  const unsigned u = blockIdx.x;
  const int b_loc = (u & 7) | ((u >> 9) << 3);   // XCD-affine: frame's 64 blocks on one XCD
  const int inner = (u >> 3) & 63;
  const int atile = inner >> 1;                  // 0..31 (8 a's each)
  const int dh = inner & 1;                      // d-half
  const int b = bBase + b_loc;
  const int lane = t & 63;
  const int wv = t >> 6;                         // 0..3
  const int l31 = lane & 31;
  const int hi = lane >> 5;

  if (t < 192) ((float4*)bbs)[t] = ((const float4*)(bb + b * (L_ * 3)))[t];
  __syncthreads();

  bf16x8 afr[8];
  const bfh* abase = x2g + ((size_t)(b_loc * 128 + atile * 4 + wv)) * 4096 + l31 * 8;
#pragma unroll
  for (int kk = 0; kk < 8; ++kk)
    afr[kk] = *(const bf16x8*)(abase + (kk * 2 + hi) * 256);

  const int aglob = atile * 8 + 2 * wv + hi;
  const float bax0 = bbs[aglob * 3 + 0];
  const float bax1 = bbs[aglob * 3 + 1];
  const float bax2 = bbs[aglob * 3 + 2];

  float accX[16], accY[16], accZ[16], accS[16];
#pragma unroll
  for (int q = 0; q < 16; ++q) { accX[q] = 0.f; accY[q] = 0.f; accZ[q] = 0.f; accS[q] = 0.f; }

  const bfh* xb = xTg + (size_t)b * 32768 + hi * 256 + l31 * 8;
  bf16x8 bcur[8], bnxt[8];
#pragma unroll
  for (int kk = 0; kk < 8; ++kk)
    bcur[kk] = *(const bf16x8*)(xb + (size_t)(dh * 4) * 4096 + kk * 512);

#pragma unroll
  for (int dt = 0; dt < 4; ++dt) {
    const int dtg = dh * 4 + dt;
    if (dt < 3) {
#pragma unroll
      for (int kk = 0; kk < 8; ++kk)
        bnxt[kk] = *(const bf16x8*)(xb + (size_t)(dtg + 1) * 4096 + kk * 512);
    }
    f32x16 acc;
#pragma unroll
    for (int q = 0; q < 16; ++q) acc[q] = 0.f;
#pragma unroll
    for (int kk = 0; kk < 8; ++kk)
      acc = __builtin_amdgcn_mfma_f32_32x32x16_bf16(afr[kk], bcur[kk], acc, 0, 0, 0);
    const int d = dtg * 32 + l31;
    const float dx = bax0 - bbs[d * 3 + 0];
    const float dy = bax1 - bbs[d * 3 + 1];
    const float dz = bax2 - bbs[d * 3 + 2];
    float p[16];
#pragma unroll
    for (int q = 0; q < 16; ++q) p[q] = EXP2(acc[q]);
    const float s0 = (p[0] + p[1]) + (p[2] + p[3]);
    const float s1 = (p[4] + p[5]) + (p[6] + p[7]);
    const float s2 = (p[8] + p[9]) + (p[10] + p[11]);
    const float s3 = (p[12] + p[13]) + (p[14] + p[15]);
    const float S = (s0 + s1) + (s2 + s3);
    const float inv = __builtin_amdgcn_rcpf(S);
    const float dxn = dx * inv, dyn = dy * inv, dzn = dz * inv;
#pragma unroll
    for (int q = 0; q < 16; ++q) {
      accS[q] = fmaf(p[q], inv, accS[q]);
      accX[q] = fmaf(p[q], dxn, accX[q]);
      accY[q] = fmaf(p[q], dyn, accY[q]);
      accZ[q] = fmaf(p[q], dzn, accZ[q]);
    }
#pragma unroll
    for (int kk = 0; kk < 8; ++kk) bcur[kk] = bnxt[kk];
  }

  float vk[3] = {0.f, 0.f, 0.f};
#pragma unroll
  for (int c = 0; c < 16; ++c) {
#pragma unroll
    for (int k = 0; k < 3; ++k) {
      const float* w2 = t2w + (k * C_ + c) * 3;
      vk[k] += w2[0] * accX[c] + w2[1] * accY[c] + w2[2] * accZ[c] +
               t2b[k * C_ + c] * accS[c];
    }
  }
#pragma unroll
  for (int m = 1; m <= 16; m <<= 1) {
    vk[0] += __shfl_xor(vk[0], m);
    vk[1] += __shfl_xor(vk[1], m);
    vk[2] += __shfl_xor(vk[2], m);
  }
  if (l31 == 0) {
#pragma unroll
    for (int k = 0; k < 3; ++k)
      vkp[(((size_t)b * 2 + dh) * L_ + aglob) * 3 + k] = vk[k];
  }
}

// ---------------- mse over frames (combines vd partials on the fly) ----------------
__global__ void k_mse(const float* __restrict__ vkp, const float* __restrict__ bb,
                      float* __restrict__ out) {
  const int b = blockIdx.x;
  const int t = threadIdx.x;
  const int bp1 = b + 1;
  float v = 0.f;
#pragma unroll
  for (int k = 0; k < 3; ++k) {
    float vd = vkp[(((size_t)bp1 * 2 + 0) * L_ + t) * 3 + k] +
               vkp[(((size_t)bp1 * 2 + 1) * L_ + t) * 3 + k];
    float nb = bb[((size_t)bp1 * L_ + t) * 3 + k] + STEP_ * vd;
    float d = nb - bb[((size_t)b * L_ + t) * 3 + k];
    v += d * d;
  }
  for (int o = 32; o > 0; o >>= 1) v += __shfl_down(v, o);
  __shared__ float wsum[4];
  if ((t & 63) == 0) wsum[t >> 6] = v;
  __syncthreads();
  if (t == 0) out[b] = (wsum[0] + wsum[1] + wsum[2] + wsum[3]) * (1.0f / L_);
}

extern "C" void kernel_launch(void* const* d_in, const int* in_sizes, int n_in,
                              void* d_out, int out_size, void* d_ws, size_t ws_size,
                              hipStream_t stream) {
  const int* aa = (const int*)d_in[0];
  const float* bb = (const float*)d_in[1];
  const float* emb = (const float*)d_in[2];
  const float* conv_w = (const float*)d_in[3];
  const float* conv_b = (const float*)d_in[4];
  const float* t1w = (const float*)d_in[5];
  const float* t1b = (const float*)d_in[6];
  const float* t2w = (const float*)d_in[7];
  const float* t2b = (const float*)d_in[8];
  float* out = (float*)d_out;

  char* ws = (char*)d_ws;
  bfh* xA = (bfh*)ws;                           // 4 MB row-major intermediate
  bfh* xTg = (bfh*)(ws + 4194304);              // 4 MB frag-layout x
  bfh* t1wb = (bfh*)(ws + 8388608);             // 512 KB
  bfh* wT = (bfh*)(ws + 8912896);               // 640 KB
  float* vkp = (float*)(ws + 9568256);          // 384 KB vd partials
  bfh* x2g = (bfh*)(ws + 10485760);             // 32 or 64 MB frag-layout x2
  bfh* xB = (bfh*)(ws + 10485760);              // aliases x2g (dead before k_x2)

  const int NPREP = NL_ * K_ * E_ * E_ + 2048 * 128;
  k_prep<<<(NPREP + 255) / 256, 256, 0, stream>>>(conv_w, t1w, wT, t1wb);

  // conv stack: emb -> xB -> xA -> xB -> xTg (frag layout), 16-row tiles
  k_conv0<<<dim3(L_ / 16, B_), 512, 0, stream>>>(aa, emb, wT, conv_b, xB);
  k_conv<<<dim3(L_ / 16, B_), 512, 0, stream>>>(xB, wT + (size_t)1 * K_ * E_ * E_,
                                                conv_b + 1 * E_, xA);
  k_conv<<<dim3(L_ / 16, B_), 512, 0, stream>>>(xA, wT + (size_t)2 * K_ * E_ * E_,
                                                conv_b + 2 * E_, xB);
  k_conv_last<<<dim3(L_ / 16, B_), 512, 0, stream>>>(xB, wT + (size_t)3 * K_ * E_ * E_,
                                                     conv_b + 3 * E_, xTg);

  const size_t need1 = 10485760ull + 67108864ull;
  if (ws_size >= need1) {
    k_x2<<<B_ * 8, 512, 0, stream>>>(xTg, t1wb, t1b, x2g, 0);
    k_pair<<<B_ * 64, 256, 0, stream>>>(xTg, bb, x2g, t2w, t2b, vkp, 0);
  } else {
    for (int pass = 0; pass < 2; ++pass) {
      const int bBase = pass * 32;
      k_x2<<<32 * 8, 512, 0, stream>>>(xTg, t1wb, t1b, x2g, bBase);
      k_pair<<<32 * 64, 256, 0, stream>>>(xTg, bb, x2g, t2w, t2b, vkp, bBase);
    }
  }

  k_mse<<<B_ - 1, 256, 0, stream>>>(vkp, bb, out);
}